// Round 1
// baseline (449.591 us; speedup 1.0000x reference)
//
#include <hip/hip_runtime.h>

#define MAX_TRUE 128

__device__ __forceinline__ float softplusf_(float x) {
    return fmaxf(x, 0.0f) + log1pf(expf(-fabsf(x)));
}
__device__ __forceinline__ float bcef_(float l, float t) {
    return softplusf_(l) - l * t;
}
__device__ __forceinline__ float sigmoidf_(float x) {
    return 1.0f / (1.0f + expf(-x));
}

// Phase 1: per (scale-slot, batch) gather first <=128 true boxes in flat order.
// One wave (64 threads) per block; deterministic ballot-scan preserves order.
__global__ void gather_kernel(const float* __restrict__ yt, int S,
                              float* __restrict__ boxes, int* __restrict__ counts,
                              int slot_base) {
    int b = blockIdx.x;
    int lane = threadIdx.x;  // blockDim.x == 64
    int N = S * S * 3;
    const float* base = yt + (size_t)b * N * 85;
    int slot = slot_base + b;
    float* bo = boxes + (size_t)slot * MAX_TRUE * 4;
    int count = 0;
    for (int i0 = 0; i0 < N && count < MAX_TRUE; i0 += 64) {
        int i = i0 + lane;
        float obj = (i < N) ? base[(size_t)i * 85 + 4] : 0.0f;
        unsigned long long m = __ballot(obj > 0.5f);
        int ofs = __popcll(m & ((1ull << lane) - 1ull));
        if (obj > 0.5f) {
            int idx = count + ofs;
            if (idx < MAX_TRUE) {
                const float* src = base + (size_t)i * 85;
                bo[idx * 4 + 0] = src[0];
                bo[idx * 4 + 1] = src[1];
                bo[idx * 4 + 2] = src[2];
                bo[idx * 4 + 3] = src[3];
            }
        }
        count += __popcll(m);
    }
    if (lane == 0) counts[slot] = min(count, MAX_TRUE);
}

// Phase 2: per-cell loss. grid = (ceil(H*W/256), 3 anchors, B)
__global__ void loss_kernel(const float* __restrict__ fm, const float* __restrict__ yt,
                            int H, int W,
                            float aw0, float ah0, float aw1, float ah1, float aw2, float ah2,
                            const float* __restrict__ boxes, const int* __restrict__ counts,
                            int slot_base, float* __restrict__ accum) {
    __shared__ float sb[MAX_TRUE * 4];
    __shared__ float part[4][4];
    int b = blockIdx.z, a = blockIdx.y;
    int tid = threadIdx.x;
    int slot = slot_base + b;
    int cnt = counts[slot];
    for (int i = tid; i < cnt * 4; i += blockDim.x)
        sb[i] = boxes[(size_t)slot * MAX_TRUE * 4 + i];
    __syncthreads();

    int HW = H * W;
    int hw = blockIdx.x * blockDim.x + tid;
    float lxy = 0.f, lwh = 0.f, lconf = 0.f, lcls = 0.f;
    if (hw < HW) {
        int h = hw / W, w = hw - h * W;
        const float* f = fm + (((size_t)b * 3 + a) * 85) * HW + hw;
        const float* y = yt + ((((size_t)b * H + h) * W + w) * 3 + a) * 85;
        float l0 = f[0], l1 = f[(size_t)HW], l2 = f[2 * (size_t)HW],
              l3 = f[3 * (size_t)HW], l4 = f[4 * (size_t)HW];
        float y0 = y[0], y1 = y[1], y2 = y[2], y3 = y[3], obj = y[4];
        float gx = (float)w, gy = (float)h;
        float aw = (a == 0) ? aw0 : ((a == 1) ? aw1 : aw2);
        float ah = (a == 0) ? ah0 : ((a == 1) ? ah1 : ah2);
        const float inv_in = 1.0f / 608.0f;
        // decode pred box (ref: pred_x=(sig+gx)/H, pred_y=(sig+gy)/W; H==W)
        float px = (sigmoidf_(l0) + gx) / (float)H;
        float py = (sigmoidf_(l1) + gy) / (float)W;
        float pw = aw * expf(l2) * inv_in;
        float ph = ah * expf(l3) * inv_in;
        float pminx = px - 0.5f * pw, pmaxx = px + 0.5f * pw;
        float pminy = py - 0.5f * ph, pmaxy = py + 0.5f * ph;
        float pa = pw * ph;
        float best = 0.0f;
        for (int i = 0; i < cnt; ++i) {
            float bx = sb[i * 4 + 0], by = sb[i * 4 + 1];
            float bw = sb[i * 4 + 2], bh = sb[i * 4 + 3];
            float ix = fminf(pmaxx, bx + 0.5f * bw) - fmaxf(pminx, bx - 0.5f * bw);
            float iy = fminf(pmaxy, by + 0.5f * bh) - fmaxf(pminy, by - 0.5f * bh);
            ix = fmaxf(ix, 0.0f);
            iy = fmaxf(iy, 0.0f);
            float inter = ix * iy;
            float iou = inter / (pa + bw * bh - inter);
            best = fmaxf(best, iou);
        }
        float ignore = (best < 0.5f) ? 1.0f : 0.0f;
        float bc = bcef_(l4, obj);
        lconf = obj * bc + (1.0f - obj) * bc * ignore;
        if (obj > 0.5f) {
            float bscale = 2.0f - y2 * y3;
            float ttx = y0 * (float)H - gx;
            float tty = y1 * (float)W - gy;
            lxy = bscale * (bcef_(l0, ttx) + bcef_(l1, tty));
            float tw = logf(y2 / aw * 608.0f);
            float th = logf(y3 / ah * 608.0f);
            float dw = l2 - tw, dh = l3 - th;
            lwh = bscale * (dw * dw + dh * dh);
            float c = 0.f;
            for (int k = 0; k < 80; ++k)
                c += bcef_(f[(size_t)(5 + k) * HW], y[5 + k]);
            lcls = c;
        }
    }
    // block reduce (4 waves of 64)
    int wid = tid >> 6, ln = tid & 63;
    #pragma unroll
    for (int o = 32; o > 0; o >>= 1) {
        lxy += __shfl_down(lxy, o);
        lwh += __shfl_down(lwh, o);
        lconf += __shfl_down(lconf, o);
        lcls += __shfl_down(lcls, o);
    }
    if (ln == 0) {
        part[wid][0] = lxy; part[wid][1] = lwh;
        part[wid][2] = lconf; part[wid][3] = lcls;
    }
    __syncthreads();
    if (tid == 0) {
        float s0 = 0.f, s1 = 0.f, s2 = 0.f, s3 = 0.f;
        int nw = blockDim.x >> 6;
        for (int i = 0; i < nw; ++i) {
            s0 += part[i][0]; s1 += part[i][1];
            s2 += part[i][2]; s3 += part[i][3];
        }
        atomicAdd(&accum[0], s0);
        atomicAdd(&accum[1], s1);
        atomicAdd(&accum[2], s2);
        atomicAdd(&accum[3], s3);
    }
}

__global__ void finalize_kernel(const float* __restrict__ accum, float* __restrict__ out,
                                float invB) {
    float a0 = accum[0] * invB;
    float a1 = accum[1] * invB;
    float a2 = accum[2] * invB;
    float a3 = accum[3] * invB;
    out[1] = a0; out[2] = a1; out[3] = a2; out[4] = a3;
    out[0] = a0 + a1 + a2 + a3;
}

extern "C" void kernel_launch(void* const* d_in, const int* in_sizes, int n_in,
                              void* d_out, int out_size, void* d_ws, size_t ws_size,
                              hipStream_t stream) {
    const float* fm[3] = {(const float*)d_in[0], (const float*)d_in[1], (const float*)d_in[2]};
    const float* yt[3] = {(const float*)d_in[3], (const float*)d_in[4], (const float*)d_in[5]};
    float* out = (float*)d_out;

    float* accum = (float*)d_ws;                               // 4 floats
    int* counts = (int*)((char*)d_ws + 16);                    // 48 ints
    float* boxes = (float*)((char*)d_ws + 16 + 48 * 4);        // 48*128*4 floats

    const int B = 16;
    const int S[3] = {19, 38, 76};
    // ANCHOR_MASK = [[6,7,8],[3,4,5],[0,1,2]]
    const float A[3][6] = {
        {116.f, 90.f, 156.f, 198.f, 373.f, 326.f},
        {30.f, 61.f, 62.f, 45.f, 59.f, 119.f},
        {10.f, 13.f, 16.f, 30.f, 33.f, 23.f},
    };

    hipMemsetAsync(accum, 0, 16, stream);

    for (int s = 0; s < 3; ++s) {
        gather_kernel<<<B, 64, 0, stream>>>(yt[s], S[s], boxes, counts, s * B);
    }
    for (int s = 0; s < 3; ++s) {
        int HW = S[s] * S[s];
        dim3 grid((HW + 255) / 256, 3, B);
        loss_kernel<<<grid, 256, 0, stream>>>(fm[s], yt[s], S[s], S[s],
                                              A[s][0], A[s][1], A[s][2], A[s][3], A[s][4], A[s][5],
                                              boxes, counts, s * B, accum);
    }
    finalize_kernel<<<1, 1, 0, stream>>>(accum, out, 1.0f / (float)B);
}

// Round 2
// 331.071 us; speedup vs baseline: 1.3580x; 1.3580x over previous
//
#include <hip/hip_runtime.h>

#define MAX_TRUE 128
#define MAX_CAND 512

__device__ __forceinline__ float softplusf_(float x) {
    return fmaxf(x, 0.0f) + log1pf(expf(-fabsf(x)));
}
__device__ __forceinline__ float bcef_(float l, float t) {
    return softplusf_(l) - l * t;
}
__device__ __forceinline__ float sigmoidf_(float x) {
    return 1.0f / (1.0f + expf(-x));
}

// Phase 1a: fully-parallel candidate collection. One thread per cell.
// Records flat cell index so exact first-128 order can be recovered if needed.
__global__ void cand_kernel(const float* __restrict__ yt, int N /*S*S*3*/,
                            int slot_base,
                            float* __restrict__ cand /*[48][MAX_CAND][5]*/,
                            int* __restrict__ cnt /*[48]*/) {
    int idx = blockIdx.x * blockDim.x + threadIdx.x;
    int b = blockIdx.y;
    if (idx >= N) return;
    const float* src = yt + ((size_t)b * N + idx) * 85;
    float obj = src[4];
    if (obj > 0.5f) {
        int slot = slot_base + b;
        int pos = atomicAdd(&cnt[slot], 1);
        if (pos < MAX_CAND) {
            float* d = cand + ((size_t)slot * MAX_CAND + pos) * 5;
            d[0] = src[0];
            d[1] = src[1];
            d[2] = src[2];
            d[3] = src[3];
            ((int*)d)[4] = idx;
        }
    }
}

// Phase 1b: per-slot selection of <=128 boxes. If count<=128, order is
// irrelevant (IoU max over set) -> direct copy. Else bitonic-sort by flat
// index and keep the 128 smallest (== reference's stable argsort take).
__global__ void select_boxes(const float* __restrict__ cand, const int* __restrict__ cnt,
                             float* __restrict__ boxes /*[48][MAX_TRUE][4]*/,
                             int* __restrict__ counts /*[48]*/) {
    __shared__ int key[MAX_CAND];
    __shared__ short perm[MAX_CAND];
    int slot = blockIdx.x;
    int t = threadIdx.x;  // blockDim.x == MAX_CAND
    int c = min(cnt[slot], MAX_CAND);
    const float* cb = cand + (size_t)slot * MAX_CAND * 5;
    if (c > MAX_TRUE) {
        key[t] = (t < c) ? ((const int*)cb)[t * 5 + 4] : 0x7FFFFFFF;
        perm[t] = (short)t;
        for (int k = 2; k <= MAX_CAND; k <<= 1) {
            for (int j = k >> 1; j > 0; j >>= 1) {
                __syncthreads();
                int ixj = t ^ j;
                if (ixj > t) {
                    bool asc = ((t & k) == 0);
                    int a = key[t], bk = key[ixj];
                    if ((a > bk) == asc) {
                        key[t] = bk; key[ixj] = a;
                        short p = perm[t]; perm[t] = perm[ixj]; perm[ixj] = p;
                    }
                }
            }
        }
        __syncthreads();
        if (t < MAX_TRUE) {
            int s = perm[t];
            float* d = boxes + ((size_t)slot * MAX_TRUE + t) * 4;
            d[0] = cb[s * 5 + 0];
            d[1] = cb[s * 5 + 1];
            d[2] = cb[s * 5 + 2];
            d[3] = cb[s * 5 + 3];
        }
    } else {
        if (t < c) {
            float* d = boxes + ((size_t)slot * MAX_TRUE + t) * 4;
            d[0] = cb[t * 5 + 0];
            d[1] = cb[t * 5 + 1];
            d[2] = cb[t * 5 + 2];
            d[3] = cb[t * 5 + 3];
        }
    }
    if (t == 0) counts[slot] = min(c, MAX_TRUE);
}

// Phase 2: per-cell loss. grid = (ceil(H*W/256), 3 anchors, B)
__global__ void loss_kernel(const float* __restrict__ fm, const float* __restrict__ yt,
                            int H, int W,
                            float aw0, float ah0, float aw1, float ah1, float aw2, float ah2,
                            const float* __restrict__ boxes, const int* __restrict__ counts,
                            int slot_base, float* __restrict__ accum) {
    __shared__ float sb[MAX_TRUE * 4];
    __shared__ float part[4][4];
    int b = blockIdx.z, a = blockIdx.y;
    int tid = threadIdx.x;
    int slot = slot_base + b;
    int cnt = counts[slot];
    for (int i = tid; i < cnt * 4; i += blockDim.x)
        sb[i] = boxes[(size_t)slot * MAX_TRUE * 4 + i];
    __syncthreads();

    int HW = H * W;
    int hw = blockIdx.x * blockDim.x + tid;
    float lxy = 0.f, lwh = 0.f, lconf = 0.f, lcls = 0.f;
    if (hw < HW) {
        int h = hw / W, w = hw - h * W;
        const float* f = fm + (((size_t)b * 3 + a) * 85) * HW + hw;
        const float* y = yt + ((((size_t)b * H + h) * W + w) * 3 + a) * 85;
        float l0 = f[0], l1 = f[(size_t)HW], l2 = f[2 * (size_t)HW],
              l3 = f[3 * (size_t)HW], l4 = f[4 * (size_t)HW];
        float y0 = y[0], y1 = y[1], y2 = y[2], y3 = y[3], obj = y[4];
        float gx = (float)w, gy = (float)h;
        float aw = (a == 0) ? aw0 : ((a == 1) ? aw1 : aw2);
        float ah = (a == 0) ? ah0 : ((a == 1) ? ah1 : ah2);
        const float inv_in = 1.0f / 608.0f;
        float px = (sigmoidf_(l0) + gx) / (float)H;
        float py = (sigmoidf_(l1) + gy) / (float)W;
        float pw = aw * expf(l2) * inv_in;
        float ph = ah * expf(l3) * inv_in;
        float pminx = px - 0.5f * pw, pmaxx = px + 0.5f * pw;
        float pminy = py - 0.5f * ph, pmaxy = py + 0.5f * ph;
        float pa = pw * ph;
        float best = 0.0f;
        for (int i = 0; i < cnt; ++i) {
            float bx = sb[i * 4 + 0], by = sb[i * 4 + 1];
            float bw = sb[i * 4 + 2], bh = sb[i * 4 + 3];
            float ix = fminf(pmaxx, bx + 0.5f * bw) - fmaxf(pminx, bx - 0.5f * bw);
            float iy = fminf(pmaxy, by + 0.5f * bh) - fmaxf(pminy, by - 0.5f * bh);
            ix = fmaxf(ix, 0.0f);
            iy = fmaxf(iy, 0.0f);
            float inter = ix * iy;
            float iou = inter / (pa + bw * bh - inter);
            best = fmaxf(best, iou);
        }
        float ignore = (best < 0.5f) ? 1.0f : 0.0f;
        float bc = bcef_(l4, obj);
        lconf = obj * bc + (1.0f - obj) * bc * ignore;
        if (obj > 0.5f) {
            float bscale = 2.0f - y2 * y3;
            float ttx = y0 * (float)H - gx;
            float tty = y1 * (float)W - gy;
            lxy = bscale * (bcef_(l0, ttx) + bcef_(l1, tty));
            float tw = logf(y2 / aw * 608.0f);
            float th = logf(y3 / ah * 608.0f);
            float dw = l2 - tw, dh = l3 - th;
            lwh = bscale * (dw * dw + dh * dh);
            float c = 0.f;
            for (int k = 0; k < 80; ++k)
                c += bcef_(f[(size_t)(5 + k) * HW], y[5 + k]);
            lcls = c;
        }
    }
    int wid = tid >> 6, ln = tid & 63;
    #pragma unroll
    for (int o = 32; o > 0; o >>= 1) {
        lxy += __shfl_down(lxy, o);
        lwh += __shfl_down(lwh, o);
        lconf += __shfl_down(lconf, o);
        lcls += __shfl_down(lcls, o);
    }
    if (ln == 0) {
        part[wid][0] = lxy; part[wid][1] = lwh;
        part[wid][2] = lconf; part[wid][3] = lcls;
    }
    __syncthreads();
    if (tid == 0) {
        float s0 = 0.f, s1 = 0.f, s2 = 0.f, s3 = 0.f;
        int nw = blockDim.x >> 6;
        for (int i = 0; i < nw; ++i) {
            s0 += part[i][0]; s1 += part[i][1];
            s2 += part[i][2]; s3 += part[i][3];
        }
        atomicAdd(&accum[0], s0);
        atomicAdd(&accum[1], s1);
        atomicAdd(&accum[2], s2);
        atomicAdd(&accum[3], s3);
    }
}

__global__ void finalize_kernel(const float* __restrict__ accum, float* __restrict__ out,
                                float invB) {
    float a0 = accum[0] * invB;
    float a1 = accum[1] * invB;
    float a2 = accum[2] * invB;
    float a3 = accum[3] * invB;
    out[1] = a0; out[2] = a1; out[3] = a2; out[4] = a3;
    out[0] = a0 + a1 + a2 + a3;
}

extern "C" void kernel_launch(void* const* d_in, const int* in_sizes, int n_in,
                              void* d_out, int out_size, void* d_ws, size_t ws_size,
                              hipStream_t stream) {
    const float* fm[3] = {(const float*)d_in[0], (const float*)d_in[1], (const float*)d_in[2]};
    const float* yt[3] = {(const float*)d_in[3], (const float*)d_in[4], (const float*)d_in[5]};
    float* out = (float*)d_out;

    // workspace layout
    float* accum  = (float*)d_ws;                                   // 4 f
    int*   cnt    = (int*)((char*)d_ws + 16);                       // 48 i
    int*   counts = (int*)((char*)d_ws + 16 + 192);                 // 48 i
    float* boxes  = (float*)((char*)d_ws + 16 + 384);               // 48*128*4 f
    float* cand   = (float*)((char*)d_ws + 16 + 384 + 48 * MAX_TRUE * 4 * 4); // 48*512*5 f

    const int B = 16;
    const int S[3] = {19, 38, 76};
    // ANCHOR_MASK = [[6,7,8],[3,4,5],[0,1,2]]
    const float A[3][6] = {
        {116.f, 90.f, 156.f, 198.f, 373.f, 326.f},
        {30.f, 61.f, 62.f, 45.f, 59.f, 119.f},
        {10.f, 13.f, 16.f, 30.f, 33.f, 23.f},
    };

    // zero accum (16B) + cnt (192B) in one shot
    hipMemsetAsync(d_ws, 0, 16 + 192, stream);

    for (int s = 0; s < 3; ++s) {
        int N = S[s] * S[s] * 3;
        dim3 grid((N + 255) / 256, B);
        cand_kernel<<<grid, 256, 0, stream>>>(yt[s], N, s * B, cand, cnt);
    }
    select_boxes<<<48, MAX_CAND, 0, stream>>>(cand, cnt, boxes, counts);
    for (int s = 0; s < 3; ++s) {
        int HW = S[s] * S[s];
        dim3 grid((HW + 255) / 256, 3, B);
        loss_kernel<<<grid, 256, 0, stream>>>(fm[s], yt[s], S[s], S[s],
                                              A[s][0], A[s][1], A[s][2], A[s][3], A[s][4], A[s][5],
                                              boxes, counts, s * B, accum);
    }
    finalize_kernel<<<1, 1, 0, stream>>>(accum, out, 1.0f / (float)B);
}

// Round 3
// 204.588 us; speedup vs baseline: 2.1975x; 1.6182x over previous
//
#include <hip/hip_runtime.h>

#define MAX_TRUE 128
#define MAX_CAND 256

// anchors per (scale, anchor): ANCHOR_MASK = [[6,7,8],[3,4,5],[0,1,2]]
__device__ const float d_anch[3][3][2] = {
    {{116.f, 90.f}, {156.f, 198.f}, {373.f, 326.f}},
    {{30.f, 61.f}, {62.f, 45.f}, {59.f, 119.f}},
    {{10.f, 13.f}, {16.f, 30.f}, {33.f, 23.f}},
};

__device__ __forceinline__ float softplusf_(float x) {
    return fmaxf(x, 0.0f) + log1pf(expf(-fabsf(x)));
}
__device__ __forceinline__ float bcef_(float l, float t) {
    return softplusf_(l) - l * t;
}
__device__ __forceinline__ float sigmoidf_(float x) {
    return 1.0f / (1.0f + expf(-x));
}

// Phase 1: merged over all 3 scales. One thread per cell. Writes obj byte
// mask (so the loss pass never does scattered yt reads) and compacts
// candidate boxes with their flat cell index.
__global__ void cand_kernel(const float* __restrict__ yt0, const float* __restrict__ yt1,
                            const float* __restrict__ yt2,
                            unsigned char* __restrict__ objmask,
                            float* __restrict__ cand, int* __restrict__ cnt) {
    int bid = blockIdx.x;
    const float* yt;
    int s, ridx0, cells, objofs, spb;
    if (bid < 68)       { s = 0; yt = yt0; ridx0 = bid * 256;         cells = 17328;  objofs = 0;     spb = 1083;  }
    else if (bid < 339) { s = 1; yt = yt1; ridx0 = (bid - 68) * 256;  cells = 69312;  objofs = 17328; spb = 4332;  }
    else                { s = 2; yt = yt2; ridx0 = (bid - 339) * 256; cells = 277248; objofs = 86640; spb = 17328; }
    int ridx = ridx0 + threadIdx.x;
    if (ridx >= cells) return;
    const float* src = yt + (size_t)ridx * 85;
    float obj = src[4];
    objmask[objofs + ridx] = (obj > 0.5f) ? 1 : 0;
    if (obj > 0.5f) {
        int b = ridx / spb;
        int cell = ridx - b * spb;
        int slot = s * 16 + b;
        int pos = atomicAdd(&cnt[slot], 1);
        if (pos < MAX_CAND) {
            float* d = cand + ((size_t)slot * MAX_CAND + pos) * 5;
            d[0] = src[0];
            d[1] = src[1];
            d[2] = src[2];
            d[3] = src[3];
            ((int*)d)[4] = cell;
        }
    }
}

// Phase 2: per-slot box table. Always writes exactly 128 entries of
// (minx,miny,maxx,maxy,area); zero-filled beyond count (zero boxes are
// IoU-neutral). If count>128 (statistically unreachable), bitonic-sort by
// flat cell index reproduces the reference's stable first-128 selection.
__global__ void select_boxes(const float* __restrict__ cand, const int* __restrict__ cnt,
                             float* __restrict__ boxes5) {
    __shared__ int key[MAX_CAND];
    __shared__ short perm[MAX_CAND];
    int slot = blockIdx.x;
    int t = threadIdx.x;  // 256
    int c = min(cnt[slot], MAX_CAND);
    const float* cb = cand + (size_t)slot * MAX_CAND * 5;
    int src = t;
    if (c > MAX_TRUE) {
        key[t] = (t < c) ? ((const int*)cb)[t * 5 + 4] : 0x7FFFFFFF;
        perm[t] = (short)t;
        for (int k = 2; k <= MAX_CAND; k <<= 1) {
            for (int j = k >> 1; j > 0; j >>= 1) {
                __syncthreads();
                int ixj = t ^ j;
                if (ixj > t) {
                    bool asc = ((t & k) == 0);
                    int a = key[t], bk = key[ixj];
                    if ((a > bk) == asc) {
                        key[t] = bk; key[ixj] = a;
                        short p = perm[t]; perm[t] = perm[ixj]; perm[ixj] = p;
                    }
                }
            }
        }
        __syncthreads();
        src = perm[t];
    }
    if (t < MAX_TRUE) {
        float* d = boxes5 + ((size_t)slot * MAX_TRUE + t) * 5;
        if (t < c) {
            float x = cb[src * 5 + 0], y = cb[src * 5 + 1];
            float w = cb[src * 5 + 2], h = cb[src * 5 + 3];
            d[0] = x - 0.5f * w;
            d[1] = y - 0.5f * h;
            d[2] = x + 0.5f * w;
            d[3] = y + 0.5f * h;
            d[4] = w * h;
        } else {
            d[0] = 0.f; d[1] = 0.f; d[2] = 0.f; d[3] = 0.f; d[4] = 0.f;
        }
    }
}

// Phase 3: merged per-cell loss over all 3 scales.
__global__ void loss_kernel(const float* __restrict__ fm0, const float* __restrict__ fm1,
                            const float* __restrict__ fm2,
                            const float* __restrict__ yt0, const float* __restrict__ yt1,
                            const float* __restrict__ yt2,
                            const unsigned char* __restrict__ objmask,
                            const float* __restrict__ boxes5,
                            float* __restrict__ accum) {
    __shared__ float sb[MAX_TRUE * 5];
    __shared__ float part[4][4];
    int bid = blockIdx.x;
    int s, local, lnb, Sdim, objofs, spb;
    const float* fm;
    const float* yt;
    if (bid < 96)       { s = 0; local = bid;       lnb = 2;  Sdim = 19; objofs = 0;     spb = 1083;  fm = fm0; yt = yt0; }
    else if (bid < 384) { s = 1; local = bid - 96;  lnb = 6;  Sdim = 38; objofs = 17328; spb = 4332;  fm = fm1; yt = yt1; }
    else                { s = 2; local = bid - 384; lnb = 23; Sdim = 76; objofs = 86640; spb = 17328; fm = fm2; yt = yt2; }
    int ba = local / lnb;
    int chunk = local - ba * lnb;
    int a = ba % 3, b = ba / 3;
    int slot = s * 16 + b;
    int tid = threadIdx.x;
    for (int i = tid; i < MAX_TRUE * 5; i += 256)
        sb[i] = boxes5[(size_t)slot * MAX_TRUE * 5 + i];
    __syncthreads();

    int HW = Sdim * Sdim;
    int hw = chunk * 256 + tid;
    float lxy = 0.f, lwh = 0.f, lconf = 0.f, lcls = 0.f;
    if (hw < HW) {
        int h = hw / Sdim, w = hw - h * Sdim;
        const float* f = fm + ((size_t)(b * 255 + a * 85)) * HW + hw;
        float l0 = f[0], l1 = f[(size_t)HW], l2 = f[2 * (size_t)HW],
              l3 = f[3 * (size_t)HW], l4 = f[4 * (size_t)HW];
        float gx = (float)w, gy = (float)h;
        float aw = d_anch[s][a][0], ah = d_anch[s][a][1];
        const float inv_in = 1.0f / 608.0f;
        float px = (sigmoidf_(l0) + gx) / (float)Sdim;
        float py = (sigmoidf_(l1) + gy) / (float)Sdim;
        float pw = aw * expf(l2) * inv_in;
        float ph = ah * expf(l3) * inv_in;
        float pminx = px - 0.5f * pw, pmaxx = px + 0.5f * pw;
        float pminy = py - 0.5f * ph, pmaxy = py + 0.5f * ph;
        float pa = pw * ph;
        // best_iou < 0.5  <=>  max_i(3*inter_i - ta_i) < pa   (denominator > 0)
        float m = 0.f;
        #pragma unroll 8
        for (int i = 0; i < MAX_TRUE; ++i) {
            float bx0 = sb[i * 5 + 0], by0 = sb[i * 5 + 1];
            float bx1 = sb[i * 5 + 2], by1 = sb[i * 5 + 3];
            float ta = sb[i * 5 + 4];
            float ix = fminf(pmaxx, bx1) - fmaxf(pminx, bx0);
            float iy = fminf(pmaxy, by1) - fmaxf(pminy, by0);
            ix = fmaxf(ix, 0.0f);
            iy = fmaxf(iy, 0.0f);
            float inter = ix * iy;
            m = fmaxf(m, fmaf(3.0f, inter, -ta));
        }
        int cell = hw * 3 + a;
        int ob = objmask[objofs + b * spb + cell];
        float bc4 = bcef_(l4, (float)ob);
        if (ob) {
            lconf = bc4;
            const float* y = yt + ((size_t)(b * spb) + cell) * 85;
            float y0 = y[0], y1 = y[1], y2 = y[2], y3 = y[3];
            float bscale = 2.0f - y2 * y3;
            float ttx = y0 * (float)Sdim - gx;
            float tty = y1 * (float)Sdim - gy;
            lxy = bscale * (bcef_(l0, ttx) + bcef_(l1, tty));
            float tw = logf(y2 / aw * 608.0f);
            float th = logf(y3 / ah * 608.0f);
            float dw = l2 - tw, dh = l3 - th;
            lwh = bscale * (dw * dw + dh * dh);
            float c = 0.f;
            for (int k = 0; k < 80; ++k)
                c += bcef_(f[(size_t)(5 + k) * HW], y[5 + k]);
            lcls = c;
        } else {
            lconf = (m < pa) ? bc4 : 0.f;  // ignore flag folded in
        }
    }
    int wid = tid >> 6, ln = tid & 63;
    #pragma unroll
    for (int o = 32; o > 0; o >>= 1) {
        lxy += __shfl_down(lxy, o);
        lwh += __shfl_down(lwh, o);
        lconf += __shfl_down(lconf, o);
        lcls += __shfl_down(lcls, o);
    }
    if (ln == 0) {
        part[wid][0] = lxy; part[wid][1] = lwh;
        part[wid][2] = lconf; part[wid][3] = lcls;
    }
    __syncthreads();
    if (tid == 0) {
        float s0 = 0.f, s1 = 0.f, s2 = 0.f, s3 = 0.f;
        for (int i = 0; i < 4; ++i) {
            s0 += part[i][0]; s1 += part[i][1];
            s2 += part[i][2]; s3 += part[i][3];
        }
        atomicAdd(&accum[0], s0);
        atomicAdd(&accum[1], s1);
        atomicAdd(&accum[2], s2);
        atomicAdd(&accum[3], s3);
    }
}

__global__ void finalize_kernel(const float* __restrict__ accum, float* __restrict__ out,
                                float invB) {
    float a0 = accum[0] * invB;
    float a1 = accum[1] * invB;
    float a2 = accum[2] * invB;
    float a3 = accum[3] * invB;
    out[1] = a0; out[2] = a1; out[3] = a2; out[4] = a3;
    out[0] = a0 + a1 + a2 + a3;
}

extern "C" void kernel_launch(void* const* d_in, const int* in_sizes, int n_in,
                              void* d_out, int out_size, void* d_ws, size_t ws_size,
                              hipStream_t stream) {
    const float* fm0 = (const float*)d_in[0];
    const float* fm1 = (const float*)d_in[1];
    const float* fm2 = (const float*)d_in[2];
    const float* yt0 = (const float*)d_in[3];
    const float* yt1 = (const float*)d_in[4];
    const float* yt2 = (const float*)d_in[5];
    float* out = (float*)d_out;

    // workspace layout
    float* accum = (float*)d_ws;                                   // 16 B
    int* cnt = (int*)((char*)d_ws + 16);                           // 192 B
    float* boxes5 = (float*)((char*)d_ws + 208);                   // 48*128*5*4 = 122880 B
    float* cand = (float*)((char*)d_ws + 208 + 122880);            // 48*256*5*4 = 245760 B
    unsigned char* objmask = (unsigned char*)((char*)d_ws + 208 + 122880 + 245760); // 363888 B

    hipMemsetAsync(d_ws, 0, 208, stream);

    cand_kernel<<<1422, 256, 0, stream>>>(yt0, yt1, yt2, objmask, cand, cnt);
    select_boxes<<<48, MAX_CAND, 0, stream>>>(cand, cnt, boxes5);
    loss_kernel<<<1488, 256, 0, stream>>>(fm0, fm1, fm2, yt0, yt1, yt2,
                                          objmask, boxes5, accum);
    finalize_kernel<<<1, 1, 0, stream>>>(accum, out, 1.0f / 16.0f);
}

// Round 4
// 157.165 us; speedup vs baseline: 2.8606x; 1.3017x over previous
//
#include <hip/hip_runtime.h>

#define MAX_TRUE 128
#define MAX_CAND 256

// anchors per (scale, anchor): ANCHOR_MASK = [[6,7,8],[3,4,5],[0,1,2]]
__device__ const float d_anch[3][3][2] = {
    {{116.f, 90.f}, {156.f, 198.f}, {373.f, 326.f}},
    {{30.f, 61.f}, {62.f, 45.f}, {59.f, 119.f}},
    {{10.f, 13.f}, {16.f, 30.f}, {33.f, 23.f}},
};

__device__ __forceinline__ float softplusf_(float x) {
    return fmaxf(x, 0.0f) + log1pf(expf(-fabsf(x)));
}
__device__ __forceinline__ float bcef_(float l, float t) {
    return softplusf_(l) - l * t;
}
__device__ __forceinline__ float sigmoidf_(float x) {
    return 1.0f / (1.0f + expf(-x));
}

// Phase 1: merged over all 3 scales. One thread per cell. Writes obj byte
// mask and compacts candidate boxes with their flat cell index.
__global__ void cand_kernel(const float* __restrict__ yt0, const float* __restrict__ yt1,
                            const float* __restrict__ yt2,
                            unsigned char* __restrict__ objmask,
                            float* __restrict__ cand, int* __restrict__ cnt) {
    int bid = blockIdx.x;
    const float* yt;
    int s, ridx0, cells, objofs, spb;
    if (bid < 68)       { s = 0; yt = yt0; ridx0 = bid * 256;         cells = 17328;  objofs = 0;     spb = 1083;  }
    else if (bid < 339) { s = 1; yt = yt1; ridx0 = (bid - 68) * 256;  cells = 69312;  objofs = 17328; spb = 4332;  }
    else                { s = 2; yt = yt2; ridx0 = (bid - 339) * 256; cells = 277248; objofs = 86640; spb = 17328; }
    int ridx = ridx0 + threadIdx.x;
    if (ridx >= cells) return;
    const float* src = yt + (size_t)ridx * 85;
    float obj = src[4];
    objmask[objofs + ridx] = (obj > 0.5f) ? 1 : 0;
    if (obj > 0.5f) {
        int b = ridx / spb;
        int cell = ridx - b * spb;
        int slot = s * 16 + b;
        int pos = atomicAdd(&cnt[slot], 1);
        if (pos < MAX_CAND) {
            float* d = cand + ((size_t)slot * MAX_CAND + pos) * 5;
            d[0] = src[0];
            d[1] = src[1];
            d[2] = src[2];
            d[3] = src[3];
            ((int*)d)[4] = cell;
        }
    }
}

// Phase 2: per-slot box table, SoA: corners float4 + area. Exactly 128
// entries, zero-filled beyond count (zero boxes are IoU-neutral). If
// count>128 (statistically unreachable) bitonic-sort by flat cell index
// reproduces the reference's stable first-128 selection.
__global__ void select_boxes(const float* __restrict__ cand, const int* __restrict__ cnt,
                             float4* __restrict__ boxesA, float* __restrict__ boxesT,
                             int* __restrict__ counts) {
    __shared__ int key[MAX_CAND];
    __shared__ short perm[MAX_CAND];
    int slot = blockIdx.x;
    int t = threadIdx.x;  // 256
    int c = min(cnt[slot], MAX_CAND);
    const float* cb = cand + (size_t)slot * MAX_CAND * 5;
    int src = t;
    if (c > MAX_TRUE) {
        key[t] = (t < c) ? ((const int*)cb)[t * 5 + 4] : 0x7FFFFFFF;
        perm[t] = (short)t;
        for (int k = 2; k <= MAX_CAND; k <<= 1) {
            for (int j = k >> 1; j > 0; j >>= 1) {
                __syncthreads();
                int ixj = t ^ j;
                if (ixj > t) {
                    bool asc = ((t & k) == 0);
                    int a = key[t], bk = key[ixj];
                    if ((a > bk) == asc) {
                        key[t] = bk; key[ixj] = a;
                        short p = perm[t]; perm[t] = perm[ixj]; perm[ixj] = p;
                    }
                }
            }
        }
        __syncthreads();
        src = perm[t];
    }
    if (t < MAX_TRUE) {
        float4 r;
        float ta;
        if (t < c) {
            float x = cb[src * 5 + 0], y = cb[src * 5 + 1];
            float w = cb[src * 5 + 2], h = cb[src * 5 + 3];
            r.x = x - 0.5f * w; r.y = y - 0.5f * h;
            r.z = x + 0.5f * w; r.w = y + 0.5f * h;
            ta = w * h;
        } else {
            r.x = r.y = r.z = r.w = 0.f;
            ta = 0.f;
        }
        boxesA[slot * MAX_TRUE + t] = r;
        boxesT[slot * MAX_TRUE + t] = ta;
    }
    if (t == 0) counts[slot] = min(c, MAX_TRUE);
}

// Phase 3a: losses for obj cells only (~0.5% of cells), from the compact
// candidate list. One block per slot, one wave per candidate at a time,
// lane <-> class parallelism.
__global__ void obj_loss_kernel(const float* __restrict__ fm0, const float* __restrict__ fm1,
                                const float* __restrict__ fm2,
                                const float* __restrict__ yt0, const float* __restrict__ yt1,
                                const float* __restrict__ yt2,
                                const float* __restrict__ cand, const int* __restrict__ cnt,
                                float* __restrict__ accum_obj) {
    int slot = blockIdx.x;  // 48
    int wid = threadIdx.x >> 6, lane = threadIdx.x & 63;
    int s = slot >> 4, b = slot & 15;
    const float* fm = (s == 0) ? fm0 : ((s == 1) ? fm1 : fm2);
    const float* yt = (s == 0) ? yt0 : ((s == 1) ? yt1 : yt2);
    int Sdim = (s == 0) ? 19 : ((s == 1) ? 38 : 76);
    int HW = Sdim * Sdim, spb = HW * 3;
    int c = min(cnt[slot], MAX_CAND);
    float axy = 0.f, awh = 0.f, aconf = 0.f, acls = 0.f;
    for (int ci = wid; ci < c; ci += 4) {
        const float* cd = cand + ((size_t)slot * MAX_CAND + ci) * 5;
        float x = cd[0], y = cd[1], w = cd[2], h = cd[3];
        int cell = ((const int*)cd)[4];
        int hw = cell / 3, a = cell - hw * 3;
        int hh = hw / Sdim, ww = hw - hh * Sdim;
        const float* f = fm + ((size_t)(b * 255 + a * 85)) * HW + hw;
        const float* yrow = yt + ((size_t)b * spb + cell) * 85;
        // classes: lane handles k=lane (and k=64+lane for lane<16)
        float cl = 0.f;
        if (lane < 80) cl += bcef_(f[(size_t)(5 + lane) * HW], yrow[5 + lane]);
        if (lane < 16) {
            int k2 = 64 + lane;
            cl += bcef_(f[(size_t)(5 + k2) * HW], yrow[5 + k2]);
        }
        acls += cl;
        float bscale = 2.f - w * h;
        if (lane < 5) {
            float lv = f[(size_t)lane * HW];
            if (lane == 0) axy += bscale * bcef_(lv, x * (float)Sdim - (float)ww);
            else if (lane == 1) axy += bscale * bcef_(lv, y * (float)Sdim - (float)hh);
            else if (lane == 2) {
                float tw = logf(w / d_anch[s][a][0] * 608.f);
                float d = lv - tw;
                awh += bscale * d * d;
            } else if (lane == 3) {
                float th = logf(h / d_anch[s][a][1] * 608.f);
                float d = lv - th;
                awh += bscale * d * d;
            } else {
                aconf += bcef_(lv, 1.0f);
            }
        }
    }
    #pragma unroll
    for (int o = 32; o > 0; o >>= 1) {
        axy += __shfl_down(axy, o);
        awh += __shfl_down(awh, o);
        aconf += __shfl_down(aconf, o);
        acls += __shfl_down(acls, o);
    }
    if (lane == 0) {
        atomicAdd(&accum_obj[0], axy);
        atomicAdd(&accum_obj[1], awh);
        atomicAdd(&accum_obj[2], aconf);
        atomicAdd(&accum_obj[3], acls);
    }
}

// Phase 3b: dense conf loss for non-obj cells. 128-thread blocks.
__global__ void conf_kernel(const float* __restrict__ fm0, const float* __restrict__ fm1,
                            const float* __restrict__ fm2,
                            const unsigned char* __restrict__ objmask,
                            const float4* __restrict__ boxesA, const float* __restrict__ boxesT,
                            const int* __restrict__ counts,
                            float* __restrict__ partials) {
    __shared__ float4 sA[MAX_TRUE];
    __shared__ float sT[MAX_TRUE];
    int bid = blockIdx.x;
    int s, local, lnb, Sdim, objofs, spb;
    const float* fm;
    if (bid < 144)      { s = 0; local = bid;       lnb = 3;  Sdim = 19; objofs = 0;     spb = 1083;  fm = fm0; }
    else if (bid < 720) { s = 1; local = bid - 144; lnb = 12; Sdim = 38; objofs = 17328; spb = 4332;  fm = fm1; }
    else                { s = 2; local = bid - 720; lnb = 46; Sdim = 76; objofs = 86640; spb = 17328; fm = fm2; }
    int ba = local / lnb;
    int chunk = local - ba * lnb;
    int a = ba % 3, b = ba / 3;
    int slot = s * 16 + b;
    int tid = threadIdx.x;  // 128
    sA[tid] = boxesA[slot * MAX_TRUE + tid];
    sT[tid] = boxesT[slot * MAX_TRUE + tid];
    __syncthreads();
    int kr = (counts[slot] + 3) & ~3;
    int HW = Sdim * Sdim;
    int hw = chunk * 128 + tid;
    float lconf = 0.f;
    if (hw < HW) {
        int ob = objmask[objofs + b * spb + hw * 3 + a];
        const float* f = fm + ((size_t)(b * 255 + a * 85)) * HW + hw;
        float l0 = f[0], l1 = f[(size_t)HW], l2 = f[2 * (size_t)HW],
              l3 = f[3 * (size_t)HW], l4 = f[4 * (size_t)HW];
        if (!ob) {
            int h = hw / Sdim, w = hw - h * Sdim;
            float aw = d_anch[s][a][0], ah = d_anch[s][a][1];
            const float inv_in = 1.0f / 608.0f;
            float px = (sigmoidf_(l0) + (float)w) / (float)Sdim;
            float py = (sigmoidf_(l1) + (float)h) / (float)Sdim;
            float pw = aw * expf(l2) * inv_in;
            float ph = ah * expf(l3) * inv_in;
            float pminx = px - 0.5f * pw, pmaxx = px + 0.5f * pw;
            float pminy = py - 0.5f * ph, pmaxy = py + 0.5f * ph;
            float pa = pw * ph;
            // best_iou < 0.5  <=>  max_i(3*inter_i - ta_i) < pa
            float m0 = 0.f, m1 = 0.f, m2 = 0.f, m3 = 0.f;
            for (int i = 0; i < kr; i += 4) {
                float4 b0 = sA[i], b1 = sA[i + 1], b2 = sA[i + 2], b3 = sA[i + 3];
                float t0 = sT[i], t1 = sT[i + 1], t2 = sT[i + 2], t3 = sT[i + 3];
                float ix, iy;
                ix = fmaxf(fminf(pmaxx, b0.z) - fmaxf(pminx, b0.x), 0.f);
                iy = fmaxf(fminf(pmaxy, b0.w) - fmaxf(pminy, b0.y), 0.f);
                m0 = fmaxf(m0, fmaf(3.0f, ix * iy, -t0));
                ix = fmaxf(fminf(pmaxx, b1.z) - fmaxf(pminx, b1.x), 0.f);
                iy = fmaxf(fminf(pmaxy, b1.w) - fmaxf(pminy, b1.y), 0.f);
                m1 = fmaxf(m1, fmaf(3.0f, ix * iy, -t1));
                ix = fmaxf(fminf(pmaxx, b2.z) - fmaxf(pminx, b2.x), 0.f);
                iy = fmaxf(fminf(pmaxy, b2.w) - fmaxf(pminy, b2.y), 0.f);
                m2 = fmaxf(m2, fmaf(3.0f, ix * iy, -t2));
                ix = fmaxf(fminf(pmaxx, b3.z) - fmaxf(pminx, b3.x), 0.f);
                iy = fmaxf(fminf(pmaxy, b3.w) - fmaxf(pminy, b3.y), 0.f);
                m3 = fmaxf(m3, fmaf(3.0f, ix * iy, -t3));
            }
            float m = fmaxf(fmaxf(m0, m1), fmaxf(m2, m3));
            lconf = (m < pa) ? softplusf_(l4) : 0.f;
        }
    }
    // per-wave reduce; each wave writes its own partial (deterministic)
    int wid = tid >> 6;
    #pragma unroll
    for (int o = 32; o > 0; o >>= 1)
        lconf += __shfl_down(lconf, o);
    if ((tid & 63) == 0)
        partials[bid * 2 + wid] = lconf;
}

__global__ void finalize_kernel(const float* __restrict__ partials, int n,
                                const float* __restrict__ accum_obj,
                                float* __restrict__ out) {
    __shared__ float red[4];
    int tid = threadIdx.x;  // 256
    float ssum = 0.f;
    for (int i = tid; i < n; i += 256) ssum += partials[i];
    #pragma unroll
    for (int o = 32; o > 0; o >>= 1) ssum += __shfl_down(ssum, o);
    if ((tid & 63) == 0) red[tid >> 6] = ssum;
    __syncthreads();
    if (tid == 0) {
        float conf_noobj = red[0] + red[1] + red[2] + red[3];
        const float invB = 1.0f / 16.0f;
        float a0 = accum_obj[0] * invB;
        float a1 = accum_obj[1] * invB;
        float a2 = (accum_obj[2] + conf_noobj) * invB;
        float a3 = accum_obj[3] * invB;
        out[1] = a0; out[2] = a1; out[3] = a2; out[4] = a3;
        out[0] = a0 + a1 + a2 + a3;
    }
}

extern "C" void kernel_launch(void* const* d_in, const int* in_sizes, int n_in,
                              void* d_out, int out_size, void* d_ws, size_t ws_size,
                              hipStream_t stream) {
    const float* fm0 = (const float*)d_in[0];
    const float* fm1 = (const float*)d_in[1];
    const float* fm2 = (const float*)d_in[2];
    const float* yt0 = (const float*)d_in[3];
    const float* yt1 = (const float*)d_in[4];
    const float* yt2 = (const float*)d_in[5];
    float* out = (float*)d_out;

    // workspace layout (bytes)
    char* ws = (char*)d_ws;
    float* accum_obj = (float*)ws;                       // 16
    int* cnt = (int*)(ws + 16);                          // 192
    int* counts = (int*)(ws + 208);                      // 192
    float4* boxesA = (float4*)(ws + 400);                // 48*128*16 = 98304
    float* boxesT = (float*)(ws + 98704);                // 48*128*4  = 24576
    float* cand = (float*)(ws + 123280);                 // 48*256*5*4 = 245760
    unsigned char* objmask = (unsigned char*)(ws + 369040); // 363888
    float* partials = (float*)(ws + 732928);             // 5856*4 = 23424

    hipMemsetAsync(d_ws, 0, 208, stream);

    cand_kernel<<<1422, 256, 0, stream>>>(yt0, yt1, yt2, objmask, cand, cnt);
    select_boxes<<<48, MAX_CAND, 0, stream>>>(cand, cnt, boxesA, boxesT, counts);
    obj_loss_kernel<<<48, 256, 0, stream>>>(fm0, fm1, fm2, yt0, yt1, yt2,
                                            cand, cnt, accum_obj);
    conf_kernel<<<2928, 128, 0, stream>>>(fm0, fm1, fm2, objmask,
                                          boxesA, boxesT, counts, partials);
    finalize_kernel<<<1, 256, 0, stream>>>(partials, 5856, accum_obj, out);
}

// Round 5
// 151.440 us; speedup vs baseline: 2.9688x; 1.0378x over previous
//
#include <hip/hip_runtime.h>

#define MAX_TRUE 128
#define MAX_CAND 256

// anchors per (scale, anchor): ANCHOR_MASK = [[6,7,8],[3,4,5],[0,1,2]]
__device__ const float d_anch[3][3][2] = {
    {{116.f, 90.f}, {156.f, 198.f}, {373.f, 326.f}},
    {{30.f, 61.f}, {62.f, 45.f}, {59.f, 119.f}},
    {{10.f, 13.f}, {16.f, 30.f}, {33.f, 23.f}},
};

__device__ __forceinline__ float softplusf_(float x) {
    return fmaxf(x, 0.0f) + log1pf(expf(-fabsf(x)));
}
__device__ __forceinline__ float bcef_(float l, float t) {
    return softplusf_(l) - l * t;
}
__device__ __forceinline__ float sigmoidf_(float x) {
    return 1.0f / (1.0f + expf(-x));
}

// Phase 1: merged over all 3 scales. One thread per cell. Writes obj byte
// mask and compacts candidate boxes with their flat cell index.
__global__ void cand_kernel(const float* __restrict__ yt0, const float* __restrict__ yt1,
                            const float* __restrict__ yt2,
                            unsigned char* __restrict__ objmask,
                            float* __restrict__ cand, int* __restrict__ cnt) {
    int bid = blockIdx.x;
    const float* yt;
    int s, ridx0, cells, objofs, spb;
    if (bid < 68)       { s = 0; yt = yt0; ridx0 = bid * 256;         cells = 17328;  objofs = 0;     spb = 1083;  }
    else if (bid < 339) { s = 1; yt = yt1; ridx0 = (bid - 68) * 256;  cells = 69312;  objofs = 17328; spb = 4332;  }
    else                { s = 2; yt = yt2; ridx0 = (bid - 339) * 256; cells = 277248; objofs = 86640; spb = 17328; }
    int ridx = ridx0 + threadIdx.x;
    if (ridx >= cells) return;
    const float* src = yt + (size_t)ridx * 85;
    float obj = src[4];
    objmask[objofs + ridx] = (obj > 0.5f) ? 1 : 0;
    if (obj > 0.5f) {
        int b = ridx / spb;
        int cell = ridx - b * spb;
        int slot = s * 16 + b;
        int pos = atomicAdd(&cnt[slot], 1);
        if (pos < MAX_CAND) {
            float* d = cand + ((size_t)slot * MAX_CAND + pos) * 5;
            d[0] = src[0];
            d[1] = src[1];
            d[2] = src[2];
            d[3] = src[3];
            ((int*)d)[4] = cell;
        }
    }
}

// Phase 2: per-slot box table, SoA: corners float4 + area. Exactly 128
// entries, zero-filled beyond count (zero boxes are IoU-neutral). If
// count>128 (statistically unreachable) bitonic-sort by flat cell index
// reproduces the reference's stable first-128 selection.
__global__ void select_boxes(const float* __restrict__ cand, const int* __restrict__ cnt,
                             float4* __restrict__ boxesA, float* __restrict__ boxesT,
                             int* __restrict__ counts) {
    __shared__ int key[MAX_CAND];
    __shared__ short perm[MAX_CAND];
    int slot = blockIdx.x;
    int t = threadIdx.x;  // 256
    int c = min(cnt[slot], MAX_CAND);
    const float* cb = cand + (size_t)slot * MAX_CAND * 5;
    int src = t;
    if (c > MAX_TRUE) {
        key[t] = (t < c) ? ((const int*)cb)[t * 5 + 4] : 0x7FFFFFFF;
        perm[t] = (short)t;
        for (int k = 2; k <= MAX_CAND; k <<= 1) {
            for (int j = k >> 1; j > 0; j >>= 1) {
                __syncthreads();
                int ixj = t ^ j;
                if (ixj > t) {
                    bool asc = ((t & k) == 0);
                    int a = key[t], bk = key[ixj];
                    if ((a > bk) == asc) {
                        key[t] = bk; key[ixj] = a;
                        short p = perm[t]; perm[t] = perm[ixj]; perm[ixj] = p;
                    }
                }
            }
        }
        __syncthreads();
        src = perm[t];
    }
    if (t < MAX_TRUE) {
        float4 r;
        float ta;
        if (t < c) {
            float x = cb[src * 5 + 0], y = cb[src * 5 + 1];
            float w = cb[src * 5 + 2], h = cb[src * 5 + 3];
            r.x = x - 0.5f * w; r.y = y - 0.5f * h;
            r.z = x + 0.5f * w; r.w = y + 0.5f * h;
            ta = w * h;
        } else {
            r.x = r.y = r.z = r.w = 0.f;
            ta = 0.f;
        }
        boxesA[slot * MAX_TRUE + t] = r;
        boxesT[slot * MAX_TRUE + t] = ta;
    }
    if (t == 0) counts[slot] = min(c, MAX_TRUE);
}

// Phase 3a: losses for obj cells only. ONE WAVE PER CANDIDATE, no loop.
// grid = (MAX_CAND/4, 48), block = 256 (4 waves). Blocks past the count
// exit immediately.
__global__ void obj_loss_kernel(const float* __restrict__ fm0, const float* __restrict__ fm1,
                                const float* __restrict__ fm2,
                                const float* __restrict__ yt0, const float* __restrict__ yt1,
                                const float* __restrict__ yt2,
                                const float* __restrict__ cand, const int* __restrict__ cnt,
                                float* __restrict__ accum_obj) {
    int slot = blockIdx.y;
    int c = min(cnt[slot], MAX_CAND);
    if ((int)(blockIdx.x * 4) >= c) return;
    int wid = threadIdx.x >> 6, lane = threadIdx.x & 63;
    int ci = blockIdx.x * 4 + wid;
    int s = slot >> 4, b = slot & 15;
    const float* fm = (s == 0) ? fm0 : ((s == 1) ? fm1 : fm2);
    const float* yt = (s == 0) ? yt0 : ((s == 1) ? yt1 : yt2);
    int Sdim = (s == 0) ? 19 : ((s == 1) ? 38 : 76);
    int HW = Sdim * Sdim, spb = HW * 3;
    float axy = 0.f, awh = 0.f, aconf = 0.f, acls = 0.f;
    if (ci < c) {
        const float* cd = cand + ((size_t)slot * MAX_CAND + ci) * 5;
        float x = cd[0], y = cd[1], w = cd[2], h = cd[3];
        int cell = ((const int*)cd)[4];
        int hw = cell / 3, a = cell - hw * 3;
        int hh = hw / Sdim, ww = hw - hh * Sdim;
        const float* f = fm + ((size_t)(b * 255 + a * 85)) * HW + hw;
        const float* yrow = yt + ((size_t)b * spb + cell) * 85;
        // classes: lane handles k=lane, and k=64+lane for lane<16
        float cl = bcef_(f[(size_t)(5 + lane) * HW], yrow[5 + lane]);
        if (lane < 16) {
            int k2 = 64 + lane;
            cl += bcef_(f[(size_t)(5 + k2) * HW], yrow[5 + k2]);
        }
        acls = cl;
        float bscale = 2.f - w * h;
        if (lane < 5) {
            float lv = f[(size_t)lane * HW];
            if (lane == 0) axy = bscale * bcef_(lv, x * (float)Sdim - (float)ww);
            else if (lane == 1) axy = bscale * bcef_(lv, y * (float)Sdim - (float)hh);
            else if (lane == 2) {
                float tw = logf(w / d_anch[s][a][0] * 608.f);
                float d = lv - tw;
                awh = bscale * d * d;
            } else if (lane == 3) {
                float th = logf(h / d_anch[s][a][1] * 608.f);
                float d = lv - th;
                awh = bscale * d * d;
            } else {
                aconf = bcef_(lv, 1.0f);
            }
        }
    }
    #pragma unroll
    for (int o = 32; o > 0; o >>= 1) {
        axy += __shfl_down(axy, o);
        awh += __shfl_down(awh, o);
        aconf += __shfl_down(aconf, o);
        acls += __shfl_down(acls, o);
    }
    if (lane == 0) {
        atomicAdd(&accum_obj[0], axy);
        atomicAdd(&accum_obj[1], awh);
        atomicAdd(&accum_obj[2], aconf);
        atomicAdd(&accum_obj[3], acls);
    }
}

// Phase 3b: dense conf loss for non-obj cells. 128-thread blocks.
__global__ void conf_kernel(const float* __restrict__ fm0, const float* __restrict__ fm1,
                            const float* __restrict__ fm2,
                            const unsigned char* __restrict__ objmask,
                            const float4* __restrict__ boxesA, const float* __restrict__ boxesT,
                            const int* __restrict__ counts,
                            float* __restrict__ partials) {
    __shared__ float4 sA[MAX_TRUE];
    __shared__ float sT[MAX_TRUE];
    int bid = blockIdx.x;
    int s, local, lnb, Sdim, objofs, spb;
    const float* fm;
    if (bid < 144)      { s = 0; local = bid;       lnb = 3;  Sdim = 19; objofs = 0;     spb = 1083;  fm = fm0; }
    else if (bid < 720) { s = 1; local = bid - 144; lnb = 12; Sdim = 38; objofs = 17328; spb = 4332;  fm = fm1; }
    else                { s = 2; local = bid - 720; lnb = 46; Sdim = 76; objofs = 86640; spb = 17328; fm = fm2; }
    int ba = local / lnb;
    int chunk = local - ba * lnb;
    int a = ba % 3, b = ba / 3;
    int slot = s * 16 + b;
    int tid = threadIdx.x;  // 128
    sA[tid] = boxesA[slot * MAX_TRUE + tid];
    sT[tid] = boxesT[slot * MAX_TRUE + tid];
    __syncthreads();
    int kr = (counts[slot] + 3) & ~3;
    int HW = Sdim * Sdim;
    int hw = chunk * 128 + tid;
    float lconf = 0.f;
    if (hw < HW) {
        int ob = objmask[objofs + b * spb + hw * 3 + a];
        const float* f = fm + ((size_t)(b * 255 + a * 85)) * HW + hw;
        float l0 = f[0], l1 = f[(size_t)HW], l2 = f[2 * (size_t)HW],
              l3 = f[3 * (size_t)HW], l4 = f[4 * (size_t)HW];
        if (!ob) {
            int h = hw / Sdim, w = hw - h * Sdim;
            float aw = d_anch[s][a][0], ah = d_anch[s][a][1];
            const float inv_in = 1.0f / 608.0f;
            float px = (sigmoidf_(l0) + (float)w) / (float)Sdim;
            float py = (sigmoidf_(l1) + (float)h) / (float)Sdim;
            float pw = aw * expf(l2) * inv_in;
            float ph = ah * expf(l3) * inv_in;
            float pminx = px - 0.5f * pw, pmaxx = px + 0.5f * pw;
            float pminy = py - 0.5f * ph, pmaxy = py + 0.5f * ph;
            float pa = pw * ph;
            // best_iou < 0.5  <=>  max_i(3*inter_i - ta_i) < pa
            float m0 = 0.f, m1 = 0.f, m2 = 0.f, m3 = 0.f;
            for (int i = 0; i < kr; i += 4) {
                float4 b0 = sA[i], b1 = sA[i + 1], b2 = sA[i + 2], b3 = sA[i + 3];
                float t0 = sT[i], t1 = sT[i + 1], t2 = sT[i + 2], t3 = sT[i + 3];
                float ix, iy;
                ix = fmaxf(fminf(pmaxx, b0.z) - fmaxf(pminx, b0.x), 0.f);
                iy = fmaxf(fminf(pmaxy, b0.w) - fmaxf(pminy, b0.y), 0.f);
                m0 = fmaxf(m0, fmaf(3.0f, ix * iy, -t0));
                ix = fmaxf(fminf(pmaxx, b1.z) - fmaxf(pminx, b1.x), 0.f);
                iy = fmaxf(fminf(pmaxy, b1.w) - fmaxf(pminy, b1.y), 0.f);
                m1 = fmaxf(m1, fmaf(3.0f, ix * iy, -t1));
                ix = fmaxf(fminf(pmaxx, b2.z) - fmaxf(pminx, b2.x), 0.f);
                iy = fmaxf(fminf(pmaxy, b2.w) - fmaxf(pminy, b2.y), 0.f);
                m2 = fmaxf(m2, fmaf(3.0f, ix * iy, -t2));
                ix = fmaxf(fminf(pmaxx, b3.z) - fmaxf(pminx, b3.x), 0.f);
                iy = fmaxf(fminf(pmaxy, b3.w) - fmaxf(pminy, b3.y), 0.f);
                m3 = fmaxf(m3, fmaf(3.0f, ix * iy, -t3));
            }
            float m = fmaxf(fmaxf(m0, m1), fmaxf(m2, m3));
            lconf = (m < pa) ? softplusf_(l4) : 0.f;
        }
    }
    // per-wave reduce; each wave writes its own partial (deterministic)
    int wid = tid >> 6;
    #pragma unroll
    for (int o = 32; o > 0; o >>= 1)
        lconf += __shfl_down(lconf, o);
    if ((tid & 63) == 0)
        partials[bid * 2 + wid] = lconf;
}

__global__ void finalize_kernel(const float* __restrict__ partials, int n,
                                const float* __restrict__ accum_obj,
                                float* __restrict__ out) {
    __shared__ float red[4];
    int tid = threadIdx.x;  // 256
    float ssum = 0.f;
    for (int i = tid; i < n; i += 256) ssum += partials[i];
    #pragma unroll
    for (int o = 32; o > 0; o >>= 1) ssum += __shfl_down(ssum, o);
    if ((tid & 63) == 0) red[tid >> 6] = ssum;
    __syncthreads();
    if (tid == 0) {
        float conf_noobj = red[0] + red[1] + red[2] + red[3];
        const float invB = 1.0f / 16.0f;
        float a0 = accum_obj[0] * invB;
        float a1 = accum_obj[1] * invB;
        float a2 = (accum_obj[2] + conf_noobj) * invB;
        float a3 = accum_obj[3] * invB;
        out[1] = a0; out[2] = a1; out[3] = a2; out[4] = a3;
        out[0] = a0 + a1 + a2 + a3;
    }
}

extern "C" void kernel_launch(void* const* d_in, const int* in_sizes, int n_in,
                              void* d_out, int out_size, void* d_ws, size_t ws_size,
                              hipStream_t stream) {
    const float* fm0 = (const float*)d_in[0];
    const float* fm1 = (const float*)d_in[1];
    const float* fm2 = (const float*)d_in[2];
    const float* yt0 = (const float*)d_in[3];
    const float* yt1 = (const float*)d_in[4];
    const float* yt2 = (const float*)d_in[5];
    float* out = (float*)d_out;

    // workspace layout (bytes)
    char* ws = (char*)d_ws;
    float* accum_obj = (float*)ws;                       // 16
    int* cnt = (int*)(ws + 16);                          // 192
    int* counts = (int*)(ws + 208);                      // 192
    float4* boxesA = (float4*)(ws + 400);                // 48*128*16 = 98304
    float* boxesT = (float*)(ws + 98704);                // 48*128*4  = 24576
    float* cand = (float*)(ws + 123280);                 // 48*256*5*4 = 245760
    unsigned char* objmask = (unsigned char*)(ws + 369040); // 363888
    float* partials = (float*)(ws + 732928);             // 5856*4 = 23424

    hipMemsetAsync(d_ws, 0, 208, stream);

    cand_kernel<<<1422, 256, 0, stream>>>(yt0, yt1, yt2, objmask, cand, cnt);
    select_boxes<<<48, MAX_CAND, 0, stream>>>(cand, cnt, boxesA, boxesT, counts);
    obj_loss_kernel<<<dim3(MAX_CAND / 4, 48), 256, 0, stream>>>(fm0, fm1, fm2, yt0, yt1, yt2,
                                                                cand, cnt, accum_obj);
    conf_kernel<<<2928, 128, 0, stream>>>(fm0, fm1, fm2, objmask,
                                          boxesA, boxesT, counts, partials);
    finalize_kernel<<<1, 256, 0, stream>>>(partials, 5856, accum_obj, out);
}

// Round 6
// 73.293 us; speedup vs baseline: 6.1341x; 2.0662x over previous
//
#include <hip/hip_runtime.h>

#define MAX_TRUE 128
#define MAX_CAND 256
#define NBANK 128

// anchors per (scale, anchor): ANCHOR_MASK = [[6,7,8],[3,4,5],[0,1,2]]
__device__ const float d_anch[3][3][2] = {
    {{116.f, 90.f}, {156.f, 198.f}, {373.f, 326.f}},
    {{30.f, 61.f}, {62.f, 45.f}, {59.f, 119.f}},
    {{10.f, 13.f}, {16.f, 30.f}, {33.f, 23.f}},
};

__device__ __forceinline__ float softplusf_(float x) {
    return fmaxf(x, 0.0f) + log1pf(expf(-fabsf(x)));
}
__device__ __forceinline__ float bcef_(float l, float t) {
    return softplusf_(l) - l * t;
}
__device__ __forceinline__ float sigmoidf_(float x) {
    return 1.0f / (1.0f + expf(-x));
}

// Phase 1: merged over all 3 scales. One thread per cell. Writes obj byte
// mask and compacts candidate boxes with their flat cell index.
__global__ void cand_kernel(const float* __restrict__ yt0, const float* __restrict__ yt1,
                            const float* __restrict__ yt2,
                            unsigned char* __restrict__ objmask,
                            float* __restrict__ cand, int* __restrict__ cnt) {
    int bid = blockIdx.x;
    const float* yt;
    int s, ridx0, cells, objofs, spb;
    if (bid < 68)       { s = 0; yt = yt0; ridx0 = bid * 256;         cells = 17328;  objofs = 0;     spb = 1083;  }
    else if (bid < 339) { s = 1; yt = yt1; ridx0 = (bid - 68) * 256;  cells = 69312;  objofs = 17328; spb = 4332;  }
    else                { s = 2; yt = yt2; ridx0 = (bid - 339) * 256; cells = 277248; objofs = 86640; spb = 17328; }
    int ridx = ridx0 + threadIdx.x;
    if (ridx >= cells) return;
    const float* src = yt + (size_t)ridx * 85;
    float obj = src[4];
    objmask[objofs + ridx] = (obj > 0.5f) ? 1 : 0;
    if (obj > 0.5f) {
        int b = ridx / spb;
        int cell = ridx - b * spb;
        int slot = s * 16 + b;
        int pos = atomicAdd(&cnt[slot], 1);
        if (pos < MAX_CAND) {
            float* d = cand + ((size_t)slot * MAX_CAND + pos) * 5;
            d[0] = src[0];
            d[1] = src[1];
            d[2] = src[2];
            d[3] = src[3];
            ((int*)d)[4] = cell;
        }
    }
}

// Phase 2: per-slot box table, SoA: corners float4 + area. Exactly 128
// entries, zero-filled beyond count (zero boxes are IoU-neutral). If
// count>128 (statistically unreachable) bitonic-sort by flat cell index
// reproduces the reference's stable first-128 selection.
__global__ void select_boxes(const float* __restrict__ cand, const int* __restrict__ cnt,
                             float4* __restrict__ boxesA, float* __restrict__ boxesT,
                             int* __restrict__ counts) {
    __shared__ int key[MAX_CAND];
    __shared__ short perm[MAX_CAND];
    int slot = blockIdx.x;
    int t = threadIdx.x;  // 256
    int c = min(cnt[slot], MAX_CAND);
    const float* cb = cand + (size_t)slot * MAX_CAND * 5;
    int src = t;
    if (c > MAX_TRUE) {
        key[t] = (t < c) ? ((const int*)cb)[t * 5 + 4] : 0x7FFFFFFF;
        perm[t] = (short)t;
        for (int k = 2; k <= MAX_CAND; k <<= 1) {
            for (int j = k >> 1; j > 0; j >>= 1) {
                __syncthreads();
                int ixj = t ^ j;
                if (ixj > t) {
                    bool asc = ((t & k) == 0);
                    int a = key[t], bk = key[ixj];
                    if ((a > bk) == asc) {
                        key[t] = bk; key[ixj] = a;
                        short p = perm[t]; perm[t] = perm[ixj]; perm[ixj] = p;
                    }
                }
            }
        }
        __syncthreads();
        src = perm[t];
    }
    if (t < MAX_TRUE) {
        float4 r;
        float ta;
        if (t < c) {
            float x = cb[src * 5 + 0], y = cb[src * 5 + 1];
            float w = cb[src * 5 + 2], h = cb[src * 5 + 3];
            r.x = x - 0.5f * w; r.y = y - 0.5f * h;
            r.z = x + 0.5f * w; r.w = y + 0.5f * h;
            ta = w * h;
        } else {
            r.x = r.y = r.z = r.w = 0.f;
            ta = 0.f;
        }
        boxesA[slot * MAX_TRUE + t] = r;
        boxesT[slot * MAX_TRUE + t] = ta;
    }
    if (t == 0) counts[slot] = min(c, MAX_TRUE);
}

// Phase 3a: losses for obj cells only. One wave per candidate, no loop.
// grid = (MAX_CAND/4, 48), block = 256 (4 waves). Atomic accumulation is
// privatized into NBANK 64-byte-separated banks to avoid same-line
// serialization.
__global__ void obj_loss_kernel(const float* __restrict__ fm0, const float* __restrict__ fm1,
                                const float* __restrict__ fm2,
                                const float* __restrict__ yt0, const float* __restrict__ yt1,
                                const float* __restrict__ yt2,
                                const float* __restrict__ cand, const int* __restrict__ cnt,
                                float* __restrict__ banks /* NBANK x 16 floats (64B apart) */) {
    int slot = blockIdx.y;
    int c = min(cnt[slot], MAX_CAND);
    if ((int)(blockIdx.x * 4) >= c) return;
    int wid = threadIdx.x >> 6, lane = threadIdx.x & 63;
    int ci = blockIdx.x * 4 + wid;
    int s = slot >> 4, b = slot & 15;
    const float* fm = (s == 0) ? fm0 : ((s == 1) ? fm1 : fm2);
    const float* yt = (s == 0) ? yt0 : ((s == 1) ? yt1 : yt2);
    int Sdim = (s == 0) ? 19 : ((s == 1) ? 38 : 76);
    int HW = Sdim * Sdim, spb = HW * 3;
    float axy = 0.f, awh = 0.f, aconf = 0.f, acls = 0.f;
    if (ci < c) {
        const float* cd = cand + ((size_t)slot * MAX_CAND + ci) * 5;
        float x = cd[0], y = cd[1], w = cd[2], h = cd[3];
        int cell = ((const int*)cd)[4];
        int hw = cell / 3, a = cell - hw * 3;
        int hh = hw / Sdim, ww = hw - hh * Sdim;
        const float* f = fm + ((size_t)(b * 255 + a * 85)) * HW + hw;
        const float* yrow = yt + ((size_t)b * spb + cell) * 85;
        // classes: lane handles k=lane, and k=64+lane for lane<16
        float cl = bcef_(f[(size_t)(5 + lane) * HW], yrow[5 + lane]);
        if (lane < 16) {
            int k2 = 64 + lane;
            cl += bcef_(f[(size_t)(5 + k2) * HW], yrow[5 + k2]);
        }
        acls = cl;
        float bscale = 2.f - w * h;
        if (lane < 5) {
            float lv = f[(size_t)lane * HW];
            if (lane == 0) axy = bscale * bcef_(lv, x * (float)Sdim - (float)ww);
            else if (lane == 1) axy = bscale * bcef_(lv, y * (float)Sdim - (float)hh);
            else if (lane == 2) {
                float tw = logf(w / d_anch[s][a][0] * 608.f);
                float d = lv - tw;
                awh = bscale * d * d;
            } else if (lane == 3) {
                float th = logf(h / d_anch[s][a][1] * 608.f);
                float d = lv - th;
                awh = bscale * d * d;
            } else {
                aconf = bcef_(lv, 1.0f);
            }
        }
    }
    #pragma unroll
    for (int o = 32; o > 0; o >>= 1) {
        axy += __shfl_down(axy, o);
        awh += __shfl_down(awh, o);
        aconf += __shfl_down(aconf, o);
        acls += __shfl_down(acls, o);
    }
    if (lane == 0) {
        int bank = (blockIdx.y * 64 + blockIdx.x) & (NBANK - 1);
        float* bp = banks + bank * 16;  // 64B-separated
        atomicAdd(&bp[0], axy);
        atomicAdd(&bp[1], awh);
        atomicAdd(&bp[2], aconf);
        atomicAdd(&bp[3], acls);
    }
}

// Phase 3b: dense conf loss for non-obj cells. 128-thread blocks.
__global__ void conf_kernel(const float* __restrict__ fm0, const float* __restrict__ fm1,
                            const float* __restrict__ fm2,
                            const unsigned char* __restrict__ objmask,
                            const float4* __restrict__ boxesA, const float* __restrict__ boxesT,
                            const int* __restrict__ counts,
                            float* __restrict__ partials) {
    __shared__ float4 sA[MAX_TRUE];
    __shared__ float sT[MAX_TRUE];
    int bid = blockIdx.x;
    int s, local, lnb, Sdim, objofs, spb;
    const float* fm;
    if (bid < 144)      { s = 0; local = bid;       lnb = 3;  Sdim = 19; objofs = 0;     spb = 1083;  fm = fm0; }
    else if (bid < 720) { s = 1; local = bid - 144; lnb = 12; Sdim = 38; objofs = 17328; spb = 4332;  fm = fm1; }
    else                { s = 2; local = bid - 720; lnb = 46; Sdim = 76; objofs = 86640; spb = 17328; fm = fm2; }
    int ba = local / lnb;
    int chunk = local - ba * lnb;
    int a = ba % 3, b = ba / 3;
    int slot = s * 16 + b;
    int tid = threadIdx.x;  // 128
    sA[tid] = boxesA[slot * MAX_TRUE + tid];
    sT[tid] = boxesT[slot * MAX_TRUE + tid];
    __syncthreads();
    int kr = (counts[slot] + 3) & ~3;
    int HW = Sdim * Sdim;
    int hw = chunk * 128 + tid;
    float lconf = 0.f;
    if (hw < HW) {
        int ob = objmask[objofs + b * spb + hw * 3 + a];
        const float* f = fm + ((size_t)(b * 255 + a * 85)) * HW + hw;
        float l0 = f[0], l1 = f[(size_t)HW], l2 = f[2 * (size_t)HW],
              l3 = f[3 * (size_t)HW], l4 = f[4 * (size_t)HW];
        if (!ob) {
            int h = hw / Sdim, w = hw - h * Sdim;
            float aw = d_anch[s][a][0], ah = d_anch[s][a][1];
            const float inv_in = 1.0f / 608.0f;
            float px = (sigmoidf_(l0) + (float)w) / (float)Sdim;
            float py = (sigmoidf_(l1) + (float)h) / (float)Sdim;
            float pw = aw * expf(l2) * inv_in;
            float ph = ah * expf(l3) * inv_in;
            float pminx = px - 0.5f * pw, pmaxx = px + 0.5f * pw;
            float pminy = py - 0.5f * ph, pmaxy = py + 0.5f * ph;
            float pa = pw * ph;
            // best_iou < 0.5  <=>  max_i(3*inter_i - ta_i) < pa
            float m0 = 0.f, m1 = 0.f, m2 = 0.f, m3 = 0.f;
            for (int i = 0; i < kr; i += 4) {
                float4 b0 = sA[i], b1 = sA[i + 1], b2 = sA[i + 2], b3 = sA[i + 3];
                float t0 = sT[i], t1 = sT[i + 1], t2 = sT[i + 2], t3 = sT[i + 3];
                float ix, iy;
                ix = fmaxf(fminf(pmaxx, b0.z) - fmaxf(pminx, b0.x), 0.f);
                iy = fmaxf(fminf(pmaxy, b0.w) - fmaxf(pminy, b0.y), 0.f);
                m0 = fmaxf(m0, fmaf(3.0f, ix * iy, -t0));
                ix = fmaxf(fminf(pmaxx, b1.z) - fmaxf(pminx, b1.x), 0.f);
                iy = fmaxf(fminf(pmaxy, b1.w) - fmaxf(pminy, b1.y), 0.f);
                m1 = fmaxf(m1, fmaf(3.0f, ix * iy, -t1));
                ix = fmaxf(fminf(pmaxx, b2.z) - fmaxf(pminx, b2.x), 0.f);
                iy = fmaxf(fminf(pmaxy, b2.w) - fmaxf(pminy, b2.y), 0.f);
                m2 = fmaxf(m2, fmaf(3.0f, ix * iy, -t2));
                ix = fmaxf(fminf(pmaxx, b3.z) - fmaxf(pminx, b3.x), 0.f);
                iy = fmaxf(fminf(pmaxy, b3.w) - fmaxf(pminy, b3.y), 0.f);
                m3 = fmaxf(m3, fmaf(3.0f, ix * iy, -t3));
            }
            float m = fmaxf(fmaxf(m0, m1), fmaxf(m2, m3));
            lconf = (m < pa) ? softplusf_(l4) : 0.f;
        }
    }
    // per-wave reduce; each wave writes its own partial (deterministic)
    int wid = tid >> 6;
    #pragma unroll
    for (int o = 32; o > 0; o >>= 1)
        lconf += __shfl_down(lconf, o);
    if ((tid & 63) == 0)
        partials[bid * 2 + wid] = lconf;
}

__global__ void finalize_kernel(const float* __restrict__ partials, int n,
                                const float* __restrict__ banks,
                                float* __restrict__ out) {
    __shared__ float red[4][4];
    int tid = threadIdx.x;  // 256
    float ssum = 0.f;
    for (int i = tid; i < n; i += 256) ssum += partials[i];
    float oxy = 0.f, owh = 0.f, oconf = 0.f, ocls = 0.f;
    if (tid < NBANK) {
        const float* bp = banks + tid * 16;
        oxy = bp[0]; owh = bp[1]; oconf = bp[2]; ocls = bp[3];
    }
    #pragma unroll
    for (int o = 32; o > 0; o >>= 1) {
        ssum += __shfl_down(ssum, o);
        oxy += __shfl_down(oxy, o);
        owh += __shfl_down(owh, o);
        oconf += __shfl_down(oconf, o);
        ocls += __shfl_down(ocls, o);
    }
    if ((tid & 63) == 0) {
        int w = tid >> 6;
        red[w][0] = ssum + oconf;  // conf partial + bank conf
        red[w][1] = oxy;
        red[w][2] = owh;
        red[w][3] = ocls;
    }
    __syncthreads();
    if (tid == 0) {
        float conf = 0.f, xy = 0.f, wh = 0.f, cls = 0.f;
        for (int i = 0; i < 4; ++i) {
            conf += red[i][0]; xy += red[i][1]; wh += red[i][2]; cls += red[i][3];
        }
        const float invB = 1.0f / 16.0f;
        float a0 = xy * invB;
        float a1 = wh * invB;
        float a2 = conf * invB;
        float a3 = cls * invB;
        out[1] = a0; out[2] = a1; out[3] = a2; out[4] = a3;
        out[0] = a0 + a1 + a2 + a3;
    }
}

extern "C" void kernel_launch(void* const* d_in, const int* in_sizes, int n_in,
                              void* d_out, int out_size, void* d_ws, size_t ws_size,
                              hipStream_t stream) {
    const float* fm0 = (const float*)d_in[0];
    const float* fm1 = (const float*)d_in[1];
    const float* fm2 = (const float*)d_in[2];
    const float* yt0 = (const float*)d_in[3];
    const float* yt1 = (const float*)d_in[4];
    const float* yt2 = (const float*)d_in[5];
    float* out = (float*)d_out;

    // workspace layout (bytes)
    char* ws = (char*)d_ws;
    int* cnt = (int*)ws;                                  // 192
    int* counts = (int*)(ws + 192);                       // 192
    float* banks = (float*)(ws + 448);                    // 128 * 64B = 8192
    float4* boxesA = (float4*)(ws + 8640);                // 48*128*16 = 98304
    float* boxesT = (float*)(ws + 106944);                // 48*128*4  = 24576
    float* cand = (float*)(ws + 131520);                  // 48*256*5*4 = 245760
    unsigned char* objmask = (unsigned char*)(ws + 377280); // 363888
    float* partials = (float*)(ws + 741168);              // 5856*4 = 23424

    // zero cnt + banks
    hipMemsetAsync(d_ws, 0, 8640, stream);

    cand_kernel<<<1422, 256, 0, stream>>>(yt0, yt1, yt2, objmask, cand, cnt);
    select_boxes<<<48, MAX_CAND, 0, stream>>>(cand, cnt, boxesA, boxesT, counts);
    obj_loss_kernel<<<dim3(MAX_CAND / 4, 48), 256, 0, stream>>>(fm0, fm1, fm2, yt0, yt1, yt2,
                                                                cand, cnt, banks);
    conf_kernel<<<2928, 128, 0, stream>>>(fm0, fm1, fm2, objmask,
                                          boxesA, boxesT, counts, partials);
    finalize_kernel<<<1, 256, 0, stream>>>(partials, 5856, banks, out);
}